// Round 5
// baseline (809.880 us; speedup 1.0000x reference)
//
#include <hip/hip_runtime.h>
#include <hip/hip_cooperative_groups.h>

namespace cg = cooperative_groups;

typedef unsigned short u16;
typedef __attribute__((ext_vector_type(8))) short bf16x8;
typedef __attribute__((ext_vector_type(4))) float f32x4;
#define BATCH 16384
#define HSTR 1056

__device__ __forceinline__ float b2f(u16 u){ unsigned int i=((unsigned int)u)<<16; float f; __builtin_memcpy(&f,&i,4); return f; }
__device__ __forceinline__ u16 f2b(float f){ unsigned int x; __builtin_memcpy(&x,&f,4); unsigned int r=(x + 0x7fffu + ((x>>16)&1u))>>16; return (u16)r; }

// ================= 64x64 MFMA GEMM body (unchanged, proven) ==========
template<int BK>
__device__ __forceinline__ void gemm_body(const u16* __restrict__ A,
                                          const u16* __restrict__ Wt,
                                          const float* __restrict__ bias,
                                          u16* __restrict__ Ca,
                                          u16* __restrict__ Cb,
                                          int Nsplit,
                                          const float* __restrict__ asums,
                                          const float* __restrict__ asumsq,
                                          const float* __restrict__ ag,
                                          const float* __restrict__ abe,
                                          float* __restrict__ sums,
                                          float* __restrict__ sumsq,
                                          int N, int K, int n0, int m0,
                                          u16* lds, float* bnS, float* bnB){
  constexpr int STR = BK + 8;
  constexpr int EPT = BK/4;
  u16* As = lds;
  u16* Bs = lds + 64*STR;
  int tid = threadIdx.x;
  int lane = tid & 63, w = tid >> 6, quad = lane >> 4, m16 = lane & 15;
  int srow = tid >> 2, skoff = (tid & 3)*EPT;
  if (asums != nullptr){
    for (int k = tid; k < K; k += 256){
      float mean = asums[k] * (1.f/(float)BATCH);
      float var  = asumsq[k] * (1.f/(float)BATCH) - mean*mean;
      float sc   = ag[k] * rsqrtf(var + 1e-5f);
      bnS[k] = sc;
      bnB[k] = abe[k] - mean*sc;
    }
    __syncthreads();
  }
  f32x4 acc[4] = {};
  int ng = n0 + srow;
  uint4 a0, a1, b0, b1;
  {
    const u16* ap = A + (size_t)(m0+srow)*K + skoff;
    a0 = *(const uint4*)ap;
    if (EPT == 16) a1 = *(const uint4*)(ap + 8);
    if (ng < N){
      const u16* bp = Wt + (size_t)ng*K + skoff;
      b0 = *(const uint4*)bp;
      if (EPT == 16) b1 = *(const uint4*)(bp + 8);
    } else { b0 = make_uint4(0u,0u,0u,0u); b1 = b0; }
  }
  for (int k0 = 0; k0 < K; k0 += BK){
    u16 at[EPT];
    __builtin_memcpy(at, &a0, 16);
    if (EPT == 16) __builtin_memcpy(at+8, &a1, 16);
    if (asums != nullptr){
#pragma unroll
      for (int j=0;j<EPT;j++){
        float v = b2f(at[j]) * bnS[k0+skoff+j] + bnB[k0+skoff+j];
        at[j] = f2b(v > 0.f ? v : 0.f);
      }
    }
    uint4 s0, s1;
    __builtin_memcpy(&s0, at, 16);
    *(uint4*)&As[srow*STR + skoff] = s0;
    if (EPT == 16){ __builtin_memcpy(&s1, at+8, 16); *(uint4*)&As[srow*STR + skoff + 8] = s1; }
    *(uint4*)&Bs[srow*STR + skoff] = b0;
    if (EPT == 16) *(uint4*)&Bs[srow*STR + skoff + 8] = b1;
    if (k0 + BK < K){
      const u16* ap = A + (size_t)(m0+srow)*K + k0 + BK + skoff;
      a0 = *(const uint4*)ap;
      if (EPT == 16) a1 = *(const uint4*)(ap + 8);
      if (ng < N){
        const u16* bp = Wt + (size_t)ng*K + k0 + BK + skoff;
        b0 = *(const uint4*)bp;
        if (EPT == 16) b1 = *(const uint4*)(bp + 8);
      }
    }
    __syncthreads();
#pragma unroll
    for (int sub=0; sub<BK/32; sub++){
      bf16x8 bfrag = *(bf16x8*)&Bs[(w*16 + m16)*STR + sub*32 + quad*8];
#pragma unroll
      for (int mc=0;mc<4;mc++){
        bf16x8 afrag = *(bf16x8*)&As[(mc*16 + m16)*STR + sub*32 + quad*8];
        acc[mc] = __builtin_amdgcn_mfma_f32_16x16x32_bf16(afrag, bfrag, acc[mc], 0, 0, 0);
      }
    }
    __syncthreads();
  }
  int cw = n0 + w*16 + m16;
  float bvv = (bias != nullptr && cw < N) ? bias[cw] : 0.f;
  float cs = 0.f, cq = 0.f;
  u16* Cs = lds;
#pragma unroll
  for (int mc=0;mc<4;mc++)
#pragma unroll
    for (int r=0;r<4;r++){
      float v = acc[mc][r] + bvv;
      cs += v; cq += v*v;
      Cs[(mc*16 + quad*4 + r)*72 + w*16 + m16] = f2b(v);
    }
  if (sums != nullptr){
    cs += __shfl_xor(cs, 16, 64); cs += __shfl_xor(cs, 32, 64);
    cq += __shfl_xor(cq, 16, 64); cq += __shfl_xor(cq, 32, 64);
    if (quad == 0 && cw < N){ atomicAdd(&sums[cw], cs); atomicAdd(&sumsq[cw], cq); }
  }
  __syncthreads();
  int row = tid >> 2, c4 = (tid & 3)*16;
  int cg = n0 + c4;
  if (cg < N){
    u16* outp; int stride, colbase;
    if (Cb != nullptr && n0 >= Nsplit){ outp = Cb; stride = N - Nsplit; colbase = cg - Nsplit; }
    else if (Cb != nullptr){            outp = Ca; stride = Nsplit;     colbase = cg; }
    else {                              outp = Ca; stride = N;          colbase = cg; }
    uint4 p0 = *(uint4*)&Cs[row*72 + c4];
    uint4 p1 = *(uint4*)&Cs[row*72 + c4 + 8];
    *(uint4*)(outp + (size_t)(m0+row)*stride + colbase) = p0;
    *(uint4*)(outp + (size_t)(m0+row)*stride + colbase + 8) = p1;
  }
}

struct MegaArgs {
  const int* feat; const float* emb;
  const float *hb0, *mb0;
  const float *hW0, *hW1, *hW2, *mW0, *mW1, *u0w, *v1w;
  const float *hg0, *hbe0, *hb1, *hg1, *hbe1, *hb2, *hg2, *hbe2;
  const float *mb1, *mg0, *mbe0, *mg1, *mbe1;
  const float *v0, *u1, *ab0, *ab1, *gamma1, *bias1, *cw, *cb, *lw, *lb;
  u16 *H, *e, *Y0, *Y1, *M0, *Mout, *T;
  u16 *catWt, *hW1t, *hW2t, *mW1t, *u0t, *v1t;
  float *catb, *S, *hSg, *hBg, *mSg, *mBg;
  float* out;
};

__global__ __launch_bounds__(256, 4) void mega_kernel(MegaArgs a){
  __shared__ __align__(16) char smem[23424];
  cg::grid_group gg = cg::this_grid();
  const int tid = threadIdx.x;
  const int bid = blockIdx.x;
  const int nb  = gridDim.x;

  // ---------------- S0: prep (zero stats, catb, transposes, gather e) ----------------
  {
    int gi = bid*256 + tid;
    if (gi < 4480) a.S[gi] = 0.f;
    else if (gi < 5120){ int i = gi - 4480; a.catb[i] = (i < 128) ? a.hb0[i] : a.mb0[i-128]; }
    for (int c = bid; c < 1504; c += nb){
      if (c < 640){        int idx=c*256+tid;        int n=idx>>8, k=idx&255;
                           a.catWt[idx] = f2b(n<128 ? a.hW0[k*128+n] : a.mW0[k*512+(n-128)]); }
      else if (c < 672){   int idx=(c-640)*256+tid;  a.hW1t[idx]=f2b(a.hW1[(idx%128)*64   + idx/128]); }
      else if (c < 928){   int idx=(c-672)*256+tid;  a.hW2t[idx]=f2b(a.hW2[(idx%64)*1024  + idx/64]);  }
      else if (c < 1440){  int idx=(c-928)*256+tid;  a.mW1t[idx]=f2b(a.mW1[(idx%512)*256  + idx/512]); }
      else if (c < 1472){  int idx=(c-1440)*256+tid; a.u0t[idx]=f2b(a.u0w[(idx%256)*32   + idx/256]); }
      else {               int idx=(c-1472)*256+tid; a.v1t[idx]=f2b(a.v1w[(idx%32)*256   + idx/32]);  }
    }
    for (int g = bid; g < 1024; g += nb){
      int b = g*16 + (tid >> 4), f = tid & 15;
      int id = a.feat[b*16 + f];
      const float4* src = (const float4*)(a.emb + ((size_t)f*100000 + (size_t)id)*16);
      float4 v0 = src[0], v1 = src[1], v2 = src[2], v3 = src[3];
      u16 o[16] = { f2b(v0.x),f2b(v0.y),f2b(v0.z),f2b(v0.w), f2b(v1.x),f2b(v1.y),f2b(v1.z),f2b(v1.w),
                    f2b(v2.x),f2b(v2.y),f2b(v2.z),f2b(v2.w), f2b(v3.x),f2b(v3.y),f2b(v3.z),f2b(v3.w) };
      uint4 p0, p1; __builtin_memcpy(&p0, &o[0], 16); __builtin_memcpy(&p1, &o[8], 16);
      uint4* dst = (uint4*)(a.e + (size_t)b*256 + f*16);
      dst[0] = p0; dst[1] = p1;
    }
  }
  gg.sync();

  u16*  glds = (u16*)smem;
  float* bnS = (float*)(smem + 18432);
  float* bnB = (float*)(smem + 18432 + 2048);

  // ---------------- S1: e -> {Y0|M0}   N=640, K=256, 2560 tiles ----------------
  for (int t = bid; t < 2560; t += nb){
    __syncthreads();
    gemm_body<64>(a.e, a.catWt, a.catb, a.Y0, a.M0, 128,
                  nullptr, nullptr, nullptr, nullptr,
                  a.S+0, a.S+640, 640, 256, (t%10)*64, (t/10)*64, glds, bnS, bnB);
  }
  gg.sync();

  // ---------------- S2: dual  Y1 (256 tiles) + Mout (1024 tiles) ----------------
  for (int t = bid; t < 1280; t += nb){
    __syncthreads();
    if (t < 256){
      gemm_body<64>(a.Y0, a.hW1t, a.hb1, a.Y1, nullptr, 0,
                    a.S+0, a.S+640, a.hg0, a.hbe0,
                    a.S+1280, a.S+1344, 64, 128, 0, t*64, glds, bnS, bnB);
    } else {
      int q = t - 256;
      gemm_body<64>(a.M0, a.mW1t, a.mb1, a.Mout, nullptr, 0,
                    a.S+128, a.S+768, a.mg0, a.mbe0,
                    a.S+3456, a.S+3712, 256, 512, (q%4)*64, (q/4)*64, glds, bnS, bnB);
    }
  }
  gg.sync();

  // ---------------- S3: H = bnrelu(Y1) @ hW2t + hb2   N=1024, K=64, 4096 tiles ----------------
  for (int t = bid; t < 4096; t += nb){
    __syncthreads();
    gemm_body<64>(a.Y1, a.hW2t, a.hb2, a.H, nullptr, 0,
                  a.S+1280, a.S+1344, a.hg1, a.hbe1,
                  a.S+1408, a.S+2432, 1024, 64, (t%16)*64, (t/16)*64, glds, bnS, bnB);
  }
  gg.sync();

  // ---------------- S4: BN tables for adapter/final ----------------
  if (bid < 4){
    int i = bid*256 + tid;
    float mean = a.S[1408+i] * (1.f/(float)BATCH);
    float var  = a.S[2432+i] * (1.f/(float)BATCH) - mean*mean;
    float sc   = a.hg2[i] * rsqrtf(var + 1e-5f);
    a.hSg[i] = sc; a.hBg[i] = a.hbe2[i] - mean*sc;
    if (i < 256){
      float mmean = a.S[3456+i] * (1.f/(float)BATCH);
      float mvar  = a.S[3712+i] * (1.f/(float)BATCH) - mmean*mmean;
      float msc   = a.mg1[i] * rsqrtf(mvar + 1e-5f);
      a.mSg[i] = msc; a.mBg[i] = a.mbe1[i] - mmean*msc;
    }
  }
  gg.sync();

  // ---------------- S5: adapter (8 rows/tile, 2048 tiles) + T + T-stats ----------------
  {
    u16* Hs   = (u16*)smem;                 // 8*1056 u16 = 16896 B; rows 0-7 alias aS/Ts
    u16* v0s  = (u16*)(smem + 16896);       // 1024 u16
    u16* u1s  = (u16*)(smem + 18944);       // 1024 u16
    float* PT = (float*)(smem + 20992);     // 256
    float* QS = (float*)(smem + 22016);     // 256
    float* ab0s = (float*)(smem + 23040);   // 32
    int r = tid >> 5, j = tid & 31;
    {
      float4 av = *(const float4*)(a.v0 + tid*4);
      ushort4 pa = { f2b(av.x), f2b(av.y), f2b(av.z), f2b(av.w) };
      *(ushort4*)&v0s[tid*4] = pa;
      float4 b4 = *(const float4*)(a.u1 + tid*4);
      ushort4 pb = { f2b(b4.x), f2b(b4.y), f2b(b4.z), f2b(b4.w) };
      *(ushort4*)&u1s[tid*4] = pb;
      if (tid < 32) ab0s[tid] = a.ab0[tid];
    }
    __syncthreads();
    for (int t = bid; t < 2048; t += nb){
      size_t row0 = (size_t)t * 8;
      // prefetch H tile (T14 split: issue early, consume after P)
      const u16* Hb = a.H + row0*1024 + tid*8;
      uint4 h0 = *(const uint4*)(Hb);
      uint4 h1 = *(const uint4*)(Hb + 2048);
      uint4 h2 = *(const uint4*)(Hb + 4096);
      uint4 h3 = *(const uint4*)(Hb + 6144);
      // stage + activate Mout tile -> aS (= Hs[0..2047])
      {
        int el = tid*8, col = el & 255;
        uint4 mv = *(const uint4*)(a.Mout + row0*256 + el);
        float4 s0 = *(const float4*)(a.mSg + col), s1 = *(const float4*)(a.mSg + col + 4);
        float4 bb0 = *(const float4*)(a.mBg + col), bb1 = *(const float4*)(a.mBg + col + 4);
        float sv[8] = { s0.x,s0.y,s0.z,s0.w, s1.x,s1.y,s1.z,s1.w };
        float bv[8] = { bb0.x,bb0.y,bb0.z,bb0.w, bb1.x,bb1.y,bb1.z,bb1.w };
        u16 mt[8]; __builtin_memcpy(mt, &mv, 16);
#pragma unroll
        for (int q=0;q<8;q++){
          float v = b2f(mt[q]) * sv[q] + bv[q];
          mt[q] = f2b(v > 0.f ? v : 0.f);
        }
        uint4 so; __builtin_memcpy(&so, mt, 16);
        *(uint4*)&Hs[el] = so;
      }
      // P[r][j] = aS[r] . u0t[j]  (wave-local aS rows)
      {
        float accp = 0.f;
        for (int k8 = 0; k8 < 256; k8 += 8){
          uint4 vu = *(const uint4*)(a.u0t + j*256 + k8);
          uint4 va; __builtin_memcpy(&va, &Hs[r*256 + k8], 16);
          u16 ta[8], tu[8]; __builtin_memcpy(ta, &va, 16); __builtin_memcpy(tu, &vu, 16);
#pragma unroll
          for (int q=0;q<8;q++) accp += b2f(ta[q]) * b2f(tu[q]);
        }
        PT[tid] = accp;
      }
      __syncthreads();   // aS dead; Hs may be overwritten
      // Hs = relu(bn(H)) from prefetched regs + global tables
#pragma unroll
      for (int it=0; it<4; it++){
        int el2 = it*2048 + tid*8, rr = el2 >> 10, col2 = el2 & 1023;
        uint4 hv = (it==0)?h0:(it==1)?h1:(it==2)?h2:h3;
        float4 s0 = *(const float4*)(a.hSg + col2), s1 = *(const float4*)(a.hSg + col2 + 4);
        float4 bb0 = *(const float4*)(a.hBg + col2), bb1 = *(const float4*)(a.hBg + col2 + 4);
        float sv[8] = { s0.x,s0.y,s0.z,s0.w, s1.x,s1.y,s1.z,s1.w };
        float bv[8] = { bb0.x,bb0.y,bb0.z,bb0.w, bb1.x,bb1.y,bb1.z,bb1.w };
        u16 ht[8]; __builtin_memcpy(ht, &hv, 16);
#pragma unroll
        for (int q=0;q<8;q++){
          float v = b2f(ht[q]) * sv[q] + bv[q];
          ht[q] = f2b(v > 0.f ? v : 0.f);
        }
        uint4 so; __builtin_memcpy(&so, ht, 16);
        *(uint4*)&Hs[rr*HSTR + col2] = so;
      }
      __syncthreads();   // Hs visible
      // q -> t1 -> s -> z2 (wave-local)
      float acc = 0.f;
#pragma unroll
      for (int i=0;i<32;i++) acc += PT[r*32+i] * b2f(Hs[r*HSTR + i*32 + j]);
      QS[tid] = acc;
      acc = ab0s[j];
#pragma unroll
      for (int i=0;i<32;i++) acc += QS[r*32+i] * b2f(v0s[i*32+j]);
      PT[tid] = 1.f / (1.f + __expf(-acc));
      acc = 0.f;
#pragma unroll
      for (int i=0;i<32;i++) acc += PT[r*32+i] * b2f(u1s[i*32+j]);
      QS[tid] = acc;
      acc = 0.f;
#pragma unroll
      for (int i=0;i<32;i++) acc += QS[r*32+i] * b2f(Hs[r*HSTR + i*32 + j]);
      PT[tid] = b2f(f2b(acc));   // rounded z2
      __syncthreads();           // Hs reads done; Ts may alias
      // T row tile: t[r][c] = z2[r] . v1t[c] + ab1[c]
      u16* Ts = Hs;
#pragma unroll
      for (int c8=0;c8<8;c8++){
        int c = j + 32*c8;
        const u16* vp = a.v1t + (size_t)c*32;
        uint4 q0 = *(const uint4*)vp, q1 = *(const uint4*)(vp+8);
        uint4 q2 = *(const uint4*)(vp+16), q3 = *(const uint4*)(vp+24);
        u16 tv[32];
        __builtin_memcpy(tv, &q0, 16);    __builtin_memcpy(tv+8, &q1, 16);
        __builtin_memcpy(tv+16, &q2, 16); __builtin_memcpy(tv+24, &q3, 16);
        float tt = a.ab1[c];
#pragma unroll
        for (int k=0;k<32;k++) tt += PT[r*32+k] * b2f(tv[k]);
        Ts[r*264 + c] = f2b(tt);
      }
      __syncthreads();           // Ts visible
      // T stats + store
      {
        float s = 0.f, qq = 0.f;
#pragma unroll
        for (int rr=0;rr<8;rr++){ float v = b2f(Ts[rr*264 + tid]); s += v; qq += v*v; }
        atomicAdd(&a.S[3968+tid], s); atomicAdd(&a.S[4224+tid], qq);
      }
      {
        int rr = tid >> 5, cb2 = (tid & 31)*8;
        uint4 pv = *(uint4*)&Ts[rr*264 + cb2];
        *(uint4*)(a.T + (row0 + rr)*256 + cb2) = pv;
      }
      __syncthreads();           // Ts reads done before next-iter aS write
    }
  }
  gg.sync();

  // ---------------- S6: final head ----------------
  {
    float* tS = (float*)smem;
    float* tB = tS + 256;
    float* mS = tB + 256;
    float* mB = mS + 256;
    {
      int c = tid;
      float mean = a.S[3968+c] * (1.f/(float)BATCH);
      float var  = (a.S[4224+c] - mean*mean*(float)BATCH) * (1.f/(float)(BATCH-1));
      float sc   = a.gamma1[c] * rsqrtf(var + 1e-5f);
      tS[c] = sc; tB[c] = a.bias1[c] - mean*sc;
      mS[c] = a.mSg[c]; mB[c] = a.mBg[c];
    }
    __syncthreads();
    int wave = tid >> 6, lane = tid & 63, n4 = lane*4;
    for (int g = bid; g < 4096; g += nb){
      int b = g*4 + wave;
      ushort4 ev = *(const ushort4*)(a.e + (size_t)b*256 + n4);
      float ec[4] = { b2f(ev.x), b2f(ev.y), b2f(ev.z), b2f(ev.w) };
      float x[4]  = { ec[0], ec[1], ec[2], ec[3] };
      for (int i=0;i<3;i++){
        float p = 0.f;
#pragma unroll
        for (int q=0;q<4;q++) p += x[q] * a.cw[i*256 + n4 + q];
#pragma unroll
        for (int o=1;o<64;o<<=1) p += __shfl_xor(p, o, 64);
#pragma unroll
        for (int q=0;q<4;q++) x[q] = ec[q]*p + a.cb[i*256 + n4 + q] + x[q];
      }
      ushort4 tv = *(const ushort4*)(a.T  + (size_t)b*256 + n4);
      ushort4 mv = *(const ushort4*)(a.Mout + (size_t)b*256 + n4);
      float ta[4] = { b2f(tv.x), b2f(tv.y), b2f(tv.z), b2f(tv.w) };
      float ma[4] = { b2f(mv.x), b2f(mv.y), b2f(mv.z), b2f(mv.w) };
      float p = 0.f;
#pragma unroll
      for (int q=0;q<4;q++){
        int n = n4 + q;
        p += x[q] * a.lw[n];
        float mr = ma[q]*mS[n] + mB[n];
        mr = mr > 0.f ? mr : 0.f;
        float mf = tS[n]*ta[q] + tB[n] + mr;
        p += mf * a.lw[256 + n];
      }
#pragma unroll
      for (int o=32;o>0;o>>=1) p += __shfl_down(p, o, 64);
      if (lane == 0){
        float y = p + a.lb[0];
        a.out[b] = 1.f / (1.f + __expf(-y));
      }
    }
  }
}

extern "C" void kernel_launch(void* const* d_in, const int* in_sizes, int n_in,
                              void* d_out, int out_size, void* d_ws, size_t ws_size,
                              hipStream_t stream) {
  MegaArgs a;
  a.feat = (const int*)d_in[0];
  a.emb  = (const float*)d_in[2];
  a.hW0 = (const float*)d_in[3];  a.hb0 = (const float*)d_in[4];  a.hg0 = (const float*)d_in[5];  a.hbe0 = (const float*)d_in[6];
  a.hW1 = (const float*)d_in[7];  a.hb1 = (const float*)d_in[8];  a.hg1 = (const float*)d_in[9];  a.hbe1 = (const float*)d_in[10];
  a.hW2 = (const float*)d_in[11]; a.hb2 = (const float*)d_in[12]; a.hg2 = (const float*)d_in[13]; a.hbe2 = (const float*)d_in[14];
  a.cw  = (const float*)d_in[15]; a.cb  = (const float*)d_in[16];
  a.mW0 = (const float*)d_in[17]; a.mb0 = (const float*)d_in[18]; a.mg0 = (const float*)d_in[19]; a.mbe0 = (const float*)d_in[20];
  a.mW1 = (const float*)d_in[21]; a.mb1 = (const float*)d_in[22]; a.mg1 = (const float*)d_in[23]; a.mbe1 = (const float*)d_in[24];
  a.u0w = (const float*)d_in[25]; a.u1  = (const float*)d_in[26];
  a.v0  = (const float*)d_in[27]; a.v1w = (const float*)d_in[28];
  a.ab0 = (const float*)d_in[29]; a.ab1 = (const float*)d_in[30];
  a.gamma1 = (const float*)d_in[31]; a.bias1 = (const float*)d_in[32];
  a.lw  = (const float*)d_in[33]; a.lb = (const float*)d_in[34];
  a.out = (float*)d_out;

  char* base = (char*)d_ws;
  const size_t MB = 1024*1024;
  a.H    = (u16*)(base);             // [B,1024]  32 MB
  a.e    = (u16*)(base + 32*MB);     // [B,256]
  a.Y0   = (u16*)(base + 40*MB);     // [B,128]
  a.Y1   = (u16*)(base + 44*MB);     // [B,64]
  a.M0   = (u16*)(base + 48*MB);     // [B,512]
  a.Mout = (u16*)(base + 64*MB);     // [B,256]
  a.T    = (u16*)(base + 72*MB);     // [B,256]
  float* TZ = (float*)(base + 80*MB);
  a.hSg = TZ; a.hBg = TZ + 1024; a.mSg = TZ + 2048; a.mBg = TZ + 2304;
  a.catWt = (u16*)(base + 88*MB);    // [640][256]
  a.hW1t = a.catWt + 163840;         // [64][128]
  a.hW2t = a.hW1t + 8192;            // [1024][64]
  a.mW1t = a.hW2t + 65536;           // [256][512]
  a.u0t  = a.mW1t + 131072;          // [32][256]
  a.v1t  = a.u0t + 8192;             // [256][32]
  a.catb = (float*)(a.v1t + 8192);   // [640]
  a.S    = a.catb + 640;             // 4480 floats of stats

  int maxb = 0;
  hipError_t qe = hipOccupancyMaxActiveBlocksPerMultiprocessor(&maxb,
                    reinterpret_cast<const void*>(mega_kernel), 256, 0);
  if (qe != hipSuccess || maxb < 1) maxb = 2;
  if (maxb > 4) maxb = 4;
  int nblocks = 256 * maxb;

  void* kargs[] = { (void*)&a };
  hipLaunchCooperativeKernel(reinterpret_cast<const void*>(mega_kernel),
                             dim3(nblocks), dim3(256), kargs, 0, stream);
}

// Round 8
// 349.753 us; speedup vs baseline: 2.3156x; 2.3156x over previous
//
#include <hip/hip_runtime.h>

typedef unsigned short u16;
typedef __attribute__((ext_vector_type(8))) short bf16x8;
typedef __attribute__((ext_vector_type(4))) float f32x4;
#define BATCH 16384

__device__ __forceinline__ float b2f(u16 u){ unsigned int i=((unsigned int)u)<<16; float f; __builtin_memcpy(&f,&i,4); return f; }
__device__ __forceinline__ u16 f2b(float f){ unsigned int x; __builtin_memcpy(&x,&f,4); unsigned int r=(x + 0x7fffu + ((x>>16)&1u))>>16; return (u16)r; }

// ---------------- prep: zero stats + catb + transpose weights + gather ----------------
__global__ __launch_bounds__(256) void prep_kernel(float* __restrict__ S,
                                                   const float* __restrict__ hb0, const float* __restrict__ mb0,
                                                   float* __restrict__ catb,
                                                   const float* __restrict__ w0, const float* __restrict__ w1,
                                                   const float* __restrict__ w2, const float* __restrict__ w3,
                                                   const float* __restrict__ w4, const float* __restrict__ w5,
                                                   const float* __restrict__ w6,
                                                   u16* __restrict__ catWt, u16* __restrict__ t1,
                                                   u16* __restrict__ t2, u16* __restrict__ t4,
                                                   u16* __restrict__ t5, u16* __restrict__ t6,
                                                   const int* __restrict__ ids,
                                                   const float* __restrict__ emb,
                                                   u16* __restrict__ e){
  int blk = blockIdx.x;
  int tid = threadIdx.x;
  if (blk < 18){
    int i = blk*256 + tid;
    if (i < 4480) S[i] = 0.f;
  } else if (blk == 18){
    for (int i = tid; i < 640; i += 256) catb[i] = (i < 128) ? hb0[i] : mb0[i-128];
  } else if (blk < 1523){
    int c = blk - 19;
    if (c < 640){        int idx=c*256+tid;        int n=idx>>8, k=idx&255;
                         catWt[idx] = f2b(n<128 ? w0[k*128+n] : w3[k*512+(n-128)]); }
    else if (c < 672){   int idx=(c-640)*256+tid;  t1[idx]=f2b(w1[(idx%128)*64   + idx/128]); }
    else if (c < 928){   int idx=(c-672)*256+tid;  t2[idx]=f2b(w2[(idx%64)*1024  + idx/64]);  }
    else if (c < 1440){  int idx=(c-928)*256+tid;  t4[idx]=f2b(w4[(idx%512)*256  + idx/512]); }
    else if (c < 1472){  int idx=(c-1440)*256+tid; t5[idx]=f2b(w5[(idx%256)*32   + idx/256]); }
    else {               int idx=(c-1472)*256+tid; t6[idx]=f2b(w6[(idx%32)*256   + idx/32]);  }
  } else {
    int g = blk - 1523;
    int b = g*16 + (tid >> 4), f = tid & 15;
    int id = ids[b*16 + f];
    const float4* src = (const float4*)(emb + ((size_t)f*100000 + (size_t)id)*16);
    float4 v0 = src[0], v1 = src[1], v2 = src[2], v3 = src[3];
    u16 o[16] = { f2b(v0.x),f2b(v0.y),f2b(v0.z),f2b(v0.w), f2b(v1.x),f2b(v1.y),f2b(v1.z),f2b(v1.w),
                  f2b(v2.x),f2b(v2.y),f2b(v2.z),f2b(v2.w), f2b(v3.x),f2b(v3.y),f2b(v3.z),f2b(v3.w) };
    uint4 p0, p1; __builtin_memcpy(&p0, &o[0], 16); __builtin_memcpy(&p1, &o[8], 16);
    uint4* dst = (uint4*)(e + (size_t)b*256 + f*16);
    dst[0] = p0; dst[1] = p1;
  }
}

// ================= 64x64 MFMA GEMM body (device fn), templated BK, reg-prefetch ==========
template<int BK>
__device__ __forceinline__ void gemm_body(const u16* __restrict__ A,
                                          const u16* __restrict__ Wt,
                                          const float* __restrict__ bias,
                                          u16* __restrict__ Ca,
                                          u16* __restrict__ Cb,
                                          int Nsplit,
                                          const float* __restrict__ asums,
                                          const float* __restrict__ asumsq,
                                          const float* __restrict__ ag,
                                          const float* __restrict__ abe,
                                          float* __restrict__ sums,
                                          float* __restrict__ sumsq,
                                          int N, int K, int n0, int m0,
                                          u16* lds, float* bnS, float* bnB){
  constexpr int STR = BK + 8;
  constexpr int EPT = BK/4;
  u16* As = lds;
  u16* Bs = lds + 64*STR;
  int tid = threadIdx.x;
  int lane = tid & 63, w = tid >> 6, quad = lane >> 4, m16 = lane & 15;
  int srow = tid >> 2, skoff = (tid & 3)*EPT;
  if (asums != nullptr){
    for (int k = tid; k < K; k += 256){
      float mean = asums[k] * (1.f/(float)BATCH);
      float var  = asumsq[k] * (1.f/(float)BATCH) - mean*mean;
      float sc   = ag[k] * rsqrtf(var + 1e-5f);
      bnS[k] = sc;
      bnB[k] = abe[k] - mean*sc;
    }
    __syncthreads();
  }
  f32x4 acc[4] = {};
  int ng = n0 + srow;
  uint4 a0, a1, b0, b1;
  {
    const u16* ap = A + (size_t)(m0+srow)*K + skoff;
    a0 = *(const uint4*)ap;
    if (EPT == 16) a1 = *(const uint4*)(ap + 8);
    if (ng < N){
      const u16* bp = Wt + (size_t)ng*K + skoff;
      b0 = *(const uint4*)bp;
      if (EPT == 16) b1 = *(const uint4*)(bp + 8);
    } else { b0 = make_uint4(0u,0u,0u,0u); b1 = b0; }
  }
  for (int k0 = 0; k0 < K; k0 += BK){
    u16 at[EPT];
    __builtin_memcpy(at, &a0, 16);
    if (EPT == 16) __builtin_memcpy(at+8, &a1, 16);
    if (asums != nullptr){
#pragma unroll
      for (int j=0;j<EPT;j++){
        float v = b2f(at[j]) * bnS[k0+skoff+j] + bnB[k0+skoff+j];
        at[j] = f2b(v > 0.f ? v : 0.f);
      }
    }
    uint4 s0, s1;
    __builtin_memcpy(&s0, at, 16);
    *(uint4*)&As[srow*STR + skoff] = s0;
    if (EPT == 16){ __builtin_memcpy(&s1, at+8, 16); *(uint4*)&As[srow*STR + skoff + 8] = s1; }
    *(uint4*)&Bs[srow*STR + skoff] = b0;
    if (EPT == 16) *(uint4*)&Bs[srow*STR + skoff + 8] = b1;
    if (k0 + BK < K){
      const u16* ap = A + (size_t)(m0+srow)*K + k0 + BK + skoff;
      a0 = *(const uint4*)ap;
      if (EPT == 16) a1 = *(const uint4*)(ap + 8);
      if (ng < N){
        const u16* bp = Wt + (size_t)ng*K + k0 + BK + skoff;
        b0 = *(const uint4*)bp;
        if (EPT == 16) b1 = *(const uint4*)(bp + 8);
      }
    }
    __syncthreads();
#pragma unroll
    for (int sub=0; sub<BK/32; sub++){
      bf16x8 bfrag = *(bf16x8*)&Bs[(w*16 + m16)*STR + sub*32 + quad*8];
#pragma unroll
      for (int mc=0;mc<4;mc++){
        bf16x8 afrag = *(bf16x8*)&As[(mc*16 + m16)*STR + sub*32 + quad*8];
        acc[mc] = __builtin_amdgcn_mfma_f32_16x16x32_bf16(afrag, bfrag, acc[mc], 0, 0, 0);
      }
    }
    __syncthreads();
  }
  int cw = n0 + w*16 + m16;
  float bvv = (bias != nullptr && cw < N) ? bias[cw] : 0.f;
  float cs = 0.f, cq = 0.f;
  u16* Cs = lds;
#pragma unroll
  for (int mc=0;mc<4;mc++)
#pragma unroll
    for (int r=0;r<4;r++){
      float v = acc[mc][r] + bvv;
      cs += v; cq += v*v;
      Cs[(mc*16 + quad*4 + r)*72 + w*16 + m16] = f2b(v);
    }
  if (sums != nullptr){
    cs += __shfl_xor(cs, 16, 64); cs += __shfl_xor(cs, 32, 64);
    cq += __shfl_xor(cq, 16, 64); cq += __shfl_xor(cq, 32, 64);
    if (quad == 0 && cw < N){ atomicAdd(&sums[cw], cs); atomicAdd(&sumsq[cw], cq); }
  }
  __syncthreads();
  int row = tid >> 2, c4 = (tid & 3)*16;
  int cg = n0 + c4;
  if (cg < N){
    u16* outp; int stride, colbase;
    if (Cb != nullptr && n0 >= Nsplit){ outp = Cb; stride = N - Nsplit; colbase = cg - Nsplit; }
    else if (Cb != nullptr){            outp = Ca; stride = Nsplit;     colbase = cg; }
    else {                              outp = Ca; stride = N;          colbase = cg; }
    uint4 p0 = *(uint4*)&Cs[row*72 + c4];
    uint4 p1 = *(uint4*)&Cs[row*72 + c4 + 8];
    *(uint4*)(outp + (size_t)(m0+row)*stride + colbase) = p0;
    *(uint4*)(outp + (size_t)(m0+row)*stride + colbase + 8) = p1;
  }
}

template<int BK>
__global__ __launch_bounds__(256) void gemm_mfma(const u16* __restrict__ A,
                                                 const u16* __restrict__ Wt,
                                                 const float* __restrict__ bias,
                                                 u16* __restrict__ Ca,
                                                 u16* __restrict__ Cb,
                                                 int Nsplit,
                                                 const float* __restrict__ asums,
                                                 const float* __restrict__ asumsq,
                                                 const float* __restrict__ ag,
                                                 const float* __restrict__ abe,
                                                 float* __restrict__ sums,
                                                 float* __restrict__ sumsq,
                                                 int N, int K){
  constexpr int STR = BK + 8;
  __shared__ __align__(16) u16 lds[64*STR*2];
  __shared__ float bnS[512], bnB[512];
  gemm_body<BK>(A, Wt, bias, Ca, Cb, Nsplit, asums, asumsq, ag, abe,
                sums, sumsq, N, K, blockIdx.x*64, blockIdx.y*64, lds, bnS, bnB);
}

// Fused launch for two independent GEMMs (Y1 and Mout) — block-uniform branch.
__global__ __launch_bounds__(256) void gemm_dual(
    const u16* __restrict__ A1, const u16* __restrict__ Wt1, const float* __restrict__ b1,
    u16* __restrict__ C1,
    const float* __restrict__ as1, const float* __restrict__ aq1,
    const float* __restrict__ g1v, const float* __restrict__ be1,
    float* __restrict__ s1, float* __restrict__ q1, int N1, int K1, int nb1, int nblk1,
    const u16* __restrict__ A2, const u16* __restrict__ Wt2, const float* __restrict__ b2,
    u16* __restrict__ C2,
    const float* __restrict__ as2, const float* __restrict__ aq2,
    const float* __restrict__ g2v, const float* __restrict__ be2,
    float* __restrict__ s2, float* __restrict__ q2, int N2, int K2, int nblk2){
  constexpr int STR = 64 + 8;
  __shared__ __align__(16) u16 lds[64*STR*2];
  __shared__ float bnS[512], bnB[512];
  int blk = blockIdx.x;
  if (blk < nb1){
    int n0 = (blk % nblk1)*64, m0 = (blk / nblk1)*64;
    gemm_body<64>(A1, Wt1, b1, C1, nullptr, 0, as1, aq1, g1v, be1,
                  s1, q1, N1, K1, n0, m0, lds, bnS, bnB);
  } else {
    int q = blk - nb1;
    int n0 = (q % nblk2)*64, m0 = (q / nblk2)*64;
    gemm_body<64>(A2, Wt2, b2, C2, nullptr, 0, as2, aq2, g2v, be2,
                  s2, q2, N2, K2, n0, m0, lds, bnS, bnB);
  }
}

// ---------------- BN tables for adapter/final: built once, read via L2 ----------------
__global__ __launch_bounds__(256) void tables_kernel(const float* __restrict__ hsums,
                                                     const float* __restrict__ hsumsq,
                                                     const float* __restrict__ hg,
                                                     const float* __restrict__ hbe,
                                                     const float* __restrict__ msums,
                                                     const float* __restrict__ msumsq,
                                                     const float* __restrict__ mg,
                                                     const float* __restrict__ mbe,
                                                     float* __restrict__ hSg,
                                                     float* __restrict__ hBg,
                                                     float* __restrict__ mSg,
                                                     float* __restrict__ mBg){
  int i = blockIdx.x*256 + threadIdx.x;
  if (i < 1024){
    float mean = hsums[i] * (1.f/(float)BATCH);
    float var  = hsumsq[i] * (1.f/(float)BATCH) - mean*mean;
    float sc   = hg[i] * rsqrtf(var + 1e-5f);
    hSg[i] = sc; hBg[i] = hbe[i] - mean*sc;
    if (i < 256){
      float mmean = msums[i] * (1.f/(float)BATCH);
      float mvar  = msumsq[i] * (1.f/(float)BATCH) - mmean*mmean;
      float msc   = mg[i] * rsqrtf(mvar + 1e-5f);
      mSg[i] = msc; mBg[i] = mbe[i] - mmean*msc;
    }
  }
}

// ---------------- adapter core: 16 rows/block, 512 threads, + fused T tail ----------
// Wave-synchronous where legal (per-wave DS ordering); 4 block barriers:
//  b1: aS reads done (Hs overwrite of alias),  b2: Hs staged (cross-wave map),
//  b3: Hs reads done (Ts aliases Hs),          b4: Ts staged (cross-wave stat read).
#define HSTR 1056
__global__ __launch_bounds__(512) void adapter_core(const u16* __restrict__ H,
                                                    const u16* __restrict__ Mout,
                                                    const u16* __restrict__ u0t,
                                                    const float* __restrict__ v0,
                                                    const float* __restrict__ u1,
                                                    const float* __restrict__ ab0,
                                                    const float* __restrict__ hSg,
                                                    const float* __restrict__ hBg,
                                                    const float* __restrict__ mSg,
                                                    const float* __restrict__ mBg,
                                                    const u16* __restrict__ v1t,
                                                    const float* __restrict__ ab1,
                                                    u16* __restrict__ T,
                                                    float* __restrict__ tsums,
                                                    float* __restrict__ tsumsq){
  __shared__ __align__(16) u16 Hs[16*HSTR];          // 33 KB; aliases aS then Ts
  __shared__ __align__(8) u16 v0s[1024], u1s[1024];  // 4 KB
  __shared__ float PT[512], QS[512];                 // 4 KB (P->t1->z2, q->s)
  __shared__ float ab0s[32];
  int tid = threadIdx.x;
  int r = tid >> 5, j = tid & 31;
  size_t row0 = (size_t)blockIdx.x * 16;
  u16* aS = Hs;   // alias: aS dead before Hs staged

  // T14 split: issue the block's H tile loads NOW; consumed in phase D after P.
  const u16* Hb = H + row0*1024 + tid*8;
  uint4 h0 = *(const uint4*)(Hb);
  uint4 h1 = *(const uint4*)(Hb + 4096);
  uint4 h2 = *(const uint4*)(Hb + 8192);
  uint4 h3 = *(const uint4*)(Hb + 12288);

  // stage + activate Mout tile in one pass
  {
    int el = tid*8, col = el & 255;
    uint4 mv = *(const uint4*)(Mout + row0*256 + el);
    float4 s0 = *(const float4*)(mSg + col), s1 = *(const float4*)(mSg + col + 4);
    float4 bb0 = *(const float4*)(mBg + col), bb1 = *(const float4*)(mBg + col + 4);
    float sv[8] = { s0.x,s0.y,s0.z,s0.w, s1.x,s1.y,s1.z,s1.w };
    float bv[8] = { bb0.x,bb0.y,bb0.z,bb0.w, bb1.x,bb1.y,bb1.z,bb1.w };
    u16 mt[8]; __builtin_memcpy(mt, &mv, 16);
#pragma unroll
    for (int q=0;q<8;q++){
      float v = b2f(mt[q]) * sv[q] + bv[q];
      mt[q] = f2b(v > 0.f ? v : 0.f);
    }
    uint4 so; __builtin_memcpy(&so, mt, 16);
    *(uint4*)&aS[el] = so;
  }
  // small operand tables (read only after barriers)
  if (tid < 256){
    float4 a = *(const float4*)(v0 + tid*4);
    ushort4 pa = { f2b(a.x), f2b(a.y), f2b(a.z), f2b(a.w) };
    *(ushort4*)&v0s[tid*4] = pa;
    float4 b4 = *(const float4*)(u1 + tid*4);
    ushort4 pb = { f2b(b4.x), f2b(b4.y), f2b(b4.z), f2b(b4.w) };
    *(ushort4*)&u1s[tid*4] = pb;
  } else if (tid < 288){
    ab0s[tid-256] = ab0[tid-256];
  }

  // P[r][j] = sum_k aS[r][k] * u0t[j][k]   (aS row r written by this wave's lanes)
  {
    float acc = 0.f;
    for (int k8 = 0; k8 < 256; k8 += 8){
      uint4 vu = *(const uint4*)(u0t + j*256 + k8);
      uint4 va; __builtin_memcpy(&va, &aS[r*256 + k8], 16);
      u16 ta[8], tu[8]; __builtin_memcpy(ta, &va, 16); __builtin_memcpy(tu, &vu, 16);
#pragma unroll
      for (int q=0;q<8;q++) acc += b2f(ta[q]) * b2f(tu[q]);
    }
    PT[tid] = acc;
  }
  __syncthreads();                 // b1: all aS reads done; alias may be overwritten

  // phase D: Hs = relu(bn(H)) from the prefetched registers + global tables
#pragma unroll
  for (int it=0; it<4; it++){
    int el = it*4096 + tid*8;
    int rr = el >> 10, col = el & 1023;
    uint4 hv = (it==0)?h0:(it==1)?h1:(it==2)?h2:h3;
    float4 s0 = *(const float4*)(hSg + col), s1 = *(const float4*)(hSg + col + 4);
    float4 bb0 = *(const float4*)(hBg + col), bb1 = *(const float4*)(hBg + col + 4);
    float sv[8] = { s0.x,s0.y,s0.z,s0.w, s1.x,s1.y,s1.z,s1.w };
    float bv[8] = { bb0.x,bb0.y,bb0.z,bb0.w, bb1.x,bb1.y,bb1.z,bb1.w };
    u16 ht[8]; __builtin_memcpy(ht, &hv, 16);
#pragma unroll
    for (int q=0;q<8;q++){
      float v = b2f(ht[q]) * sv[q] + bv[q];
      ht[q] = f2b(v > 0.f ? v : 0.f);
    }
    uint4 so; __builtin_memcpy(&so, ht, 16);
    *(uint4*)&Hs[rr*HSTR + col] = so;
  }
  __syncthreads();                 // b2: Hs visible to all

  // q -> t1 -> s -> z2 (wave-local chain)
  float acc = 0.f;
#pragma unroll
  for (int i=0;i<32;i++) acc += PT[r*32+i] * b2f(Hs[r*HSTR + i*32 + j]);
  QS[tid] = acc;
  acc = ab0s[j];
#pragma unroll
  for (int i=0;i<32;i++) acc += QS[r*32+i] * b2f(v0s[i*32+j]);
  PT[tid] = 1.f / (1.f + __expf(-acc));
  acc = 0.f;
#pragma unroll
  for (int i=0;i<32;i++) acc += PT[r*32+i] * b2f(u1s[i*32+j]);
  QS[tid] = acc;
  acc = 0.f;
#pragma unroll
  for (int i=0;i<32;i++) acc += QS[r*32+i] * b2f(Hs[r*HSTR + i*32 + j]);
  PT[tid] = b2f(f2b(acc));         // rounded z2 (bit-matches old Z2 bf16 store)
  __syncthreads();                 // b3: all Hs reads done; Ts may alias

  // T row tile: t[r][c] = z2[r] . v1t[c] + ab1[c]   (Ts aliases Hs)
  u16* Ts = Hs;
#pragma unroll
  for (int c8=0;c8<8;c8++){
    int c = j + 32*c8;
    const u16* vp = v1t + (size_t)c*32;
    uint4 q0 = *(const uint4*)vp, q1 = *(const uint4*)(vp+8);
    uint4 q2 = *(const uint4*)(vp+16), q3 = *(const uint4*)(vp+24);
    u16 tv[32];
    __builtin_memcpy(tv, &q0, 16);    __builtin_memcpy(tv+8, &q1, 16);
    __builtin_memcpy(tv+16, &q2, 16); __builtin_memcpy(tv+24, &q3, 16);
    float t = ab1[c];
#pragma unroll
    for (int k=0;k<32;k++) t += PT[r*32+k] * b2f(tv[k]);
    Ts[r*264 + c] = f2b(t);
  }
  __syncthreads();                 // b4: Ts visible

  // T stats + store
  if (tid < 256){
    float s = 0.f, qq = 0.f;
#pragma unroll
    for (int rr=0;rr<16;rr++){ float v = b2f(Ts[rr*264 + tid]); s += v; qq += v*v; }
    atomicAdd(&tsums[tid], s); atomicAdd(&tsumsq[tid], qq);
  }
  {
    int rr = tid >> 5, cb = (tid & 31)*8;
    uint4 pv = *(uint4*)&Ts[rr*264 + cb];
    *(uint4*)(T + (row0 + rr)*256 + cb) = pv;
  }
}

// ---------------- final head ----------------
__global__ __launch_bounds__(256) void final_kernel(const u16* __restrict__ e,
                                                    const float* __restrict__ cw,
                                                    const float* __restrict__ cb,
                                                    const u16* __restrict__ t,
                                                    const u16* __restrict__ mo,
                                                    const float* __restrict__ tsums,
                                                    const float* __restrict__ tsumsq,
                                                    const float* __restrict__ tg,
                                                    const float* __restrict__ tbe,
                                                    const float* __restrict__ mSg,
                                                    const float* __restrict__ mBg,
                                                    const float* __restrict__ lw,
                                                    const float* __restrict__ lb,
                                                    float* __restrict__ out){
  __shared__ float tS[256], tB[256], mS[256], mB[256];
  int tid = threadIdx.x;
  {
    int c = tid;
    float mean = tsums[c] * (1.f/(float)BATCH);
    float var  = (tsumsq[c] - mean*mean*(float)BATCH) * (1.f/(float)(BATCH-1));
    float sc   = tg[c] * rsqrtf(var + 1e-5f);
    tS[c] = sc; tB[c] = tbe[c] - mean*sc;
    mS[c] = mSg[c]; mB[c] = mBg[c];
  }
  __syncthreads();
  int wave = tid >> 6, lane = tid & 63;
  int b = blockIdx.x*4 + wave;
  int n4 = lane*4;
  ushort4 ev = *(const ushort4*)(e + (size_t)b*256 + n4);
  float ec[4] = { b2f(ev.x), b2f(ev.y), b2f(ev.z), b2f(ev.w) };
  float x[4]  = { ec[0], ec[1], ec[2], ec[3] };
  for (int i=0;i<3;i++){
    float p = 0.f;
#pragma unroll
    for (int q=0;q<4;q++) p += x[q] * cw[i*256 + n4 + q];
#pragma unroll
    for (int o=1;o<64;o<<=1) p += __shfl_xor(p, o, 64);
#pragma unroll
    for (int q=0;q<4;q++) x[q] = ec[q]*p + cb[i*256 + n4 + q] + x[q];
  }
  ushort4 tv = *(const ushort4*)(t  + (size_t)b*256 + n4);
  ushort4 mv = *(const ushort4*)(mo + (size_t)b*256 + n4);
  float ta[4] = { b2f(tv.x), b2f(tv.y), b2f(tv.z), b2f(tv.w) };
  float ma[4] = { b2f(mv.x), b2f(mv.y), b2f(mv.z), b2f(mv.w) };
  float p = 0.f;
#pragma unroll
  for (int q=0;q<4;q++){
    int n = n4 + q;
    p += x[q] * lw[n];
    float mr = ma[q]*mS[n] + mB[n];
    mr = mr > 0.f ? mr : 0.f;
    float mf = tS[n]*ta[q] + tB[n] + mr;
    p += mf * lw[256 + n];
  }
#pragma unroll
  for (int o=32;o>0;o>>=1) p += __shfl_down(p, o, 64);
  if (lane == 0){
    float y = p + lb[0];
    out[b] = 1.f / (1.f + __expf(-y));
  }
}

extern "C" void kernel_launch(void* const* d_in, const int* in_sizes, int n_in,
                              void* d_out, int out_size, void* d_ws, size_t ws_size,
                              hipStream_t stream) {
  const int B = BATCH;
  const int*   feat = (const int*)d_in[0];
  const float* emb  = (const float*)d_in[2];
  const float* hW0 = (const float*)d_in[3],  *hb0 = (const float*)d_in[4],  *hg0 = (const float*)d_in[5],  *hbe0 = (const float*)d_in[6];
  const float* hW1 = (const float*)d_in[7],  *hb1 = (const float*)d_in[8],  *hg1 = (const float*)d_in[9],  *hbe1 = (const float*)d_in[10];
  const float* hW2 = (const float*)d_in[11], *hb2 = (const float*)d_in[12], *hg2 = (const float*)d_in[13], *hbe2 = (const float*)d_in[14];
  const float* cw  = (const float*)d_in[15], *cb  = (const float*)d_in[16];
  const float* mW0 = (const float*)d_in[17], *mb0 = (const float*)d_in[18], *mg0 = (const float*)d_in[19], *mbe0 = (const float*)d_in[20];
  const float* mW1 = (const float*)d_in[21], *mb1 = (const float*)d_in[22], *mg1 = (const float*)d_in[23], *mbe1 = (const float*)d_in[24];
  const float* u0  = (const float*)d_in[25], *u1  = (const float*)d_in[26];
  const float* v0  = (const float*)d_in[27], *v1  = (const float*)d_in[28];
  const float* ab0 = (const float*)d_in[29], *ab1 = (const float*)d_in[30];
  const float* gamma1 = (const float*)d_in[31], *bias1 = (const float*)d_in[32];
  const float* lw  = (const float*)d_in[33], *lb = (const float*)d_in[34];
  float* out = (float*)d_out;

  // ---- disjoint workspace layout ----
  char* base = (char*)d_ws;
  const size_t MB = 1024*1024;
  u16* H    = (u16*)(base);             // [B,1024]  32 MB
  u16* e    = (u16*)(base + 32*MB);     // [B,256]
  u16* Y0   = (u16*)(base + 40*MB);     // [B,128]
  u16* Y1   = (u16*)(base + 44*MB);     // [B,64]
  u16* M0   = (u16*)(base + 48*MB);     // [B,512]
  u16* Mout = (u16*)(base + 64*MB);     // [B,256]
  u16* T    = (u16*)(base + 72*MB);     // [B,256]
  float* TZ = (float*)(base + 82*MB);   // BN table zone: 2560 floats
  u16* catWt= (u16*)(base + 88*MB);     // [640][256]
  u16* hW1t = catWt + 163840;           // [64][128]
  u16* hW2t = hW1t + 8192;              // [1024][64]
  u16* mW1t = hW2t + 65536;             // [256][512]
  u16* u0t  = mW1t + 131072;            // [32][256]
  u16* v1t  = u0t + 8192;               // [256][32]
  float* catb = (float*)(v1t + 8192);   // [640]
  float* S    = catb + 640;             // 4480 floats of stats

  float* hSg = TZ;                      // [1024]
  float* hBg = TZ + 1024;               // [1024]
  float* mSg = TZ + 2048;               // [256]
  float* mBg = TZ + 2304;               // [256]

  // 1. prep
  prep_kernel<<<2547, 256, 0, stream>>>(S, hb0, mb0, catb,
                                        hW0, hW1, hW2, mW0, mW1, u0, v1,
                                        catWt, hW1t, hW2t, mW1t, u0t, v1t,
                                        feat, emb, e);

  // 2. concatenated first layer: e -> {Y0 (cols<128), M0 (cols>=128)}  [N=640, K=256]
  gemm_mfma<64><<<dim3(10, B/64), 256, 0, stream>>>(e, catWt, catb, Y0, M0, 128,
      nullptr, nullptr, nullptr, nullptr, S+0, S+640, 640, 256);

  // 3. fused dual GEMM: Y1 [N=64,K=128, 256 blocks] + Mout [N=256,K=512, 1024 blocks]
  gemm_dual<<<1280, 256, 0, stream>>>(
      Y0, hW1t, hb1, Y1, S+0, S+640, hg0, hbe0, S+1280, S+1344, 64, 128, 256, 1,
      M0, mW1t, mb1, Mout, S+128, S+768, mg0, mbe0, S+3456, S+3712, 256, 512, 4);

  // 4. H [N=1024, K=64]
  gemm_mfma<64><<<dim3(16, B/64), 256, 0, stream>>>(Y1, hW2t, hb2, H, nullptr, 0,
      S+1280, S+1344, hg1, hbe1, S+1408, S+2432, 1024, 64);

  // 4b. BN tables for adapter + final (once, instead of per-block)
  tables_kernel<<<4, 256, 0, stream>>>(S+1408, S+2432, hg2, hbe2,
                                       S+3456, S+3712, mg1, mbe1,
                                       hSg, hBg, mSg, mBg);

  // 5. adapter -> T (fused T GEMM + T stats; Z2 never materialized)
  adapter_core<<<B/16, 512, 0, stream>>>(H, Mout, u0t, v0, u1, ab0,
      hSg, hBg, mSg, mBg, v1t, ab1, T, S+3968, S+4224);

  // 6. final head
  final_kernel<<<B/4, 256, 0, stream>>>(e, cw, cb, T, Mout,
      S+3968, S+4224, gamma1, bias1, mSg, mBg, lw, lb, out);
}

// Round 9
// 324.550 us; speedup vs baseline: 2.4954x; 1.0777x over previous
//
#include <hip/hip_runtime.h>

typedef unsigned short u16;
typedef __attribute__((ext_vector_type(8))) short bf16x8;
typedef __attribute__((ext_vector_type(4))) float f32x4;
#define BATCH 16384

__device__ __forceinline__ float b2f(u16 u){ unsigned int i=((unsigned int)u)<<16; float f; __builtin_memcpy(&f,&i,4); return f; }
__device__ __forceinline__ u16 f2b(float f){ unsigned int x; __builtin_memcpy(&x,&f,4); unsigned int r=(x + 0x7fffu + ((x>>16)&1u))>>16; return (u16)r; }

// ---------------- prep: zero stats + catb + transpose weights + gather ----------------
__global__ __launch_bounds__(256) void prep_kernel(float* __restrict__ S,
                                                   const float* __restrict__ hb0, const float* __restrict__ mb0,
                                                   float* __restrict__ catb,
                                                   const float* __restrict__ w0, const float* __restrict__ w1,
                                                   const float* __restrict__ w2, const float* __restrict__ w3,
                                                   const float* __restrict__ w4, const float* __restrict__ w5,
                                                   const float* __restrict__ w6,
                                                   u16* __restrict__ catWt, u16* __restrict__ t1,
                                                   u16* __restrict__ t2, u16* __restrict__ t4,
                                                   u16* __restrict__ t5, u16* __restrict__ t6,
                                                   const int* __restrict__ ids,
                                                   const float* __restrict__ emb,
                                                   u16* __restrict__ e){
  int blk = blockIdx.x;
  int tid = threadIdx.x;
  if (blk < 18){
    int i = blk*256 + tid;
    if (i < 4480) S[i] = 0.f;
  } else if (blk == 18){
    for (int i = tid; i < 640; i += 256) catb[i] = (i < 128) ? hb0[i] : mb0[i-128];
  } else if (blk < 1523){
    int c = blk - 19;
    if (c < 640){        int idx=c*256+tid;        int n=idx>>8, k=idx&255;
                         catWt[idx] = f2b(n<128 ? w0[k*128+n] : w3[k*512+(n-128)]); }
    else if (c < 672){   int idx=(c-640)*256+tid;  t1[idx]=f2b(w1[(idx%128)*64   + idx/128]); }
    else if (c < 928){   int idx=(c-672)*256+tid;  t2[idx]=f2b(w2[(idx%64)*1024  + idx/64]);  }
    else if (c < 1440){  int idx=(c-928)*256+tid;  t4[idx]=f2b(w4[(idx%512)*256  + idx/512]); }
    else if (c < 1472){  int idx=(c-1440)*256+tid; t5[idx]=f2b(w5[(idx%256)*32   + idx/256]); }
    else {               int idx=(c-1472)*256+tid; t6[idx]=f2b(w6[(idx%32)*256   + idx/32]);  }
  } else {
    int g = blk - 1523;
    int b = g*16 + (tid >> 4), f = tid & 15;
    int id = ids[b*16 + f];
    const float4* src = (const float4*)(emb + ((size_t)f*100000 + (size_t)id)*16);
    float4 v0 = src[0], v1 = src[1], v2 = src[2], v3 = src[3];
    u16 o[16] = { f2b(v0.x),f2b(v0.y),f2b(v0.z),f2b(v0.w), f2b(v1.x),f2b(v1.y),f2b(v1.z),f2b(v1.w),
                  f2b(v2.x),f2b(v2.y),f2b(v2.z),f2b(v2.w), f2b(v3.x),f2b(v3.y),f2b(v3.z),f2b(v3.w) };
    uint4 p0, p1; __builtin_memcpy(&p0, &o[0], 16); __builtin_memcpy(&p1, &o[8], 16);
    uint4* dst = (uint4*)(e + (size_t)b*256 + f*16);
    dst[0] = p0; dst[1] = p1;
  }
}

// ================= 64x64 MFMA GEMM body (device fn), templated BK, reg-prefetch ==========
template<int BK>
__device__ __forceinline__ void gemm_body(const u16* __restrict__ A,
                                          const u16* __restrict__ Wt,
                                          const float* __restrict__ bias,
                                          u16* __restrict__ Ca,
                                          u16* __restrict__ Cb,
                                          int Nsplit,
                                          const float* __restrict__ asums,
                                          const float* __restrict__ asumsq,
                                          const float* __restrict__ ag,
                                          const float* __restrict__ abe,
                                          float* __restrict__ sums,
                                          float* __restrict__ sumsq,
                                          int N, int K, int n0, int m0,
                                          u16* lds, float* bnS, float* bnB){
  constexpr int STR = BK + 8;
  constexpr int EPT = BK/4;
  u16* As = lds;
  u16* Bs = lds + 64*STR;
  int tid = threadIdx.x;
  int lane = tid & 63, w = tid >> 6, quad = lane >> 4, m16 = lane & 15;
  int srow = tid >> 2, skoff = (tid & 3)*EPT;
  if (asums != nullptr){
    for (int k = tid; k < K; k += 256){
      float mean = asums[k] * (1.f/(float)BATCH);
      float var  = asumsq[k] * (1.f/(float)BATCH) - mean*mean;
      float sc   = ag[k] * rsqrtf(var + 1e-5f);
      bnS[k] = sc;
      bnB[k] = abe[k] - mean*sc;
    }
    __syncthreads();
  }
  f32x4 acc[4] = {};
  int ng = n0 + srow;
  uint4 a0, a1, b0, b1;
  {
    const u16* ap = A + (size_t)(m0+srow)*K + skoff;
    a0 = *(const uint4*)ap;
    if (EPT == 16) a1 = *(const uint4*)(ap + 8);
    if (ng < N){
      const u16* bp = Wt + (size_t)ng*K + skoff;
      b0 = *(const uint4*)bp;
      if (EPT == 16) b1 = *(const uint4*)(bp + 8);
    } else { b0 = make_uint4(0u,0u,0u,0u); b1 = b0; }
  }
  for (int k0 = 0; k0 < K; k0 += BK){
    u16 at[EPT];
    __builtin_memcpy(at, &a0, 16);
    if (EPT == 16) __builtin_memcpy(at+8, &a1, 16);
    if (asums != nullptr){
#pragma unroll
      for (int j=0;j<EPT;j++){
        float v = b2f(at[j]) * bnS[k0+skoff+j] + bnB[k0+skoff+j];
        at[j] = f2b(v > 0.f ? v : 0.f);
      }
    }
    uint4 s0, s1;
    __builtin_memcpy(&s0, at, 16);
    *(uint4*)&As[srow*STR + skoff] = s0;
    if (EPT == 16){ __builtin_memcpy(&s1, at+8, 16); *(uint4*)&As[srow*STR + skoff + 8] = s1; }
    *(uint4*)&Bs[srow*STR + skoff] = b0;
    if (EPT == 16) *(uint4*)&Bs[srow*STR + skoff + 8] = b1;
    if (k0 + BK < K){
      const u16* ap = A + (size_t)(m0+srow)*K + k0 + BK + skoff;
      a0 = *(const uint4*)ap;
      if (EPT == 16) a1 = *(const uint4*)(ap + 8);
      if (ng < N){
        const u16* bp = Wt + (size_t)ng*K + k0 + BK + skoff;
        b0 = *(const uint4*)bp;
        if (EPT == 16) b1 = *(const uint4*)(bp + 8);
      }
    }
    __syncthreads();
#pragma unroll
    for (int sub=0; sub<BK/32; sub++){
      bf16x8 bfrag = *(bf16x8*)&Bs[(w*16 + m16)*STR + sub*32 + quad*8];
#pragma unroll
      for (int mc=0;mc<4;mc++){
        bf16x8 afrag = *(bf16x8*)&As[(mc*16 + m16)*STR + sub*32 + quad*8];
        acc[mc] = __builtin_amdgcn_mfma_f32_16x16x32_bf16(afrag, bfrag, acc[mc], 0, 0, 0);
      }
    }
    __syncthreads();
  }
  int cw = n0 + w*16 + m16;
  float bvv = (bias != nullptr && cw < N) ? bias[cw] : 0.f;
  float cs = 0.f, cq = 0.f;
  u16* Cs = lds;
#pragma unroll
  for (int mc=0;mc<4;mc++)
#pragma unroll
    for (int r=0;r<4;r++){
      float v = acc[mc][r] + bvv;
      cs += v; cq += v*v;
      Cs[(mc*16 + quad*4 + r)*72 + w*16 + m16] = f2b(v);
    }
  if (sums != nullptr){
    cs += __shfl_xor(cs, 16, 64); cs += __shfl_xor(cs, 32, 64);
    cq += __shfl_xor(cq, 16, 64); cq += __shfl_xor(cq, 32, 64);
    if (quad == 0 && cw < N){ atomicAdd(&sums[cw], cs); atomicAdd(&sumsq[cw], cq); }
  }
  __syncthreads();
  int row = tid >> 2, c4 = (tid & 3)*16;
  int cg = n0 + c4;
  if (cg < N){
    u16* outp; int stride, colbase;
    if (Cb != nullptr && n0 >= Nsplit){ outp = Cb; stride = N - Nsplit; colbase = cg - Nsplit; }
    else if (Cb != nullptr){            outp = Ca; stride = Nsplit;     colbase = cg; }
    else {                              outp = Ca; stride = N;          colbase = cg; }
    uint4 p0 = *(uint4*)&Cs[row*72 + c4];
    uint4 p1 = *(uint4*)&Cs[row*72 + c4 + 8];
    *(uint4*)(outp + (size_t)(m0+row)*stride + colbase) = p0;
    *(uint4*)(outp + (size_t)(m0+row)*stride + colbase + 8) = p1;
  }
}

template<int BK>
__global__ __launch_bounds__(256) void gemm_mfma(const u16* __restrict__ A,
                                                 const u16* __restrict__ Wt,
                                                 const float* __restrict__ bias,
                                                 u16* __restrict__ Ca,
                                                 u16* __restrict__ Cb,
                                                 int Nsplit,
                                                 const float* __restrict__ asums,
                                                 const float* __restrict__ asumsq,
                                                 const float* __restrict__ ag,
                                                 const float* __restrict__ abe,
                                                 float* __restrict__ sums,
                                                 float* __restrict__ sumsq,
                                                 int N, int K){
  constexpr int STR = BK + 8;
  __shared__ u16 lds[64*STR*2];
  __shared__ float bnS[512], bnB[512];
  gemm_body<BK>(A, Wt, bias, Ca, Cb, Nsplit, asums, asumsq, ag, abe,
                sums, sumsq, N, K, blockIdx.x*64, blockIdx.y*64, lds, bnS, bnB);
}

// Fused launch for two independent GEMMs (Y1 and Mout) — block-uniform branch.
__global__ __launch_bounds__(256) void gemm_dual(
    const u16* __restrict__ A1, const u16* __restrict__ Wt1, const float* __restrict__ b1,
    u16* __restrict__ C1,
    const float* __restrict__ as1, const float* __restrict__ aq1,
    const float* __restrict__ g1v, const float* __restrict__ be1,
    float* __restrict__ s1, float* __restrict__ q1, int N1, int K1, int nb1, int nblk1,
    const u16* __restrict__ A2, const u16* __restrict__ Wt2, const float* __restrict__ b2,
    u16* __restrict__ C2,
    const float* __restrict__ as2, const float* __restrict__ aq2,
    const float* __restrict__ g2v, const float* __restrict__ be2,
    float* __restrict__ s2, float* __restrict__ q2, int N2, int K2, int nblk2){
  constexpr int STR = 64 + 8;
  __shared__ u16 lds[64*STR*2];
  __shared__ float bnS[512], bnB[512];
  int blk = blockIdx.x;
  if (blk < nb1){
    int n0 = (blk % nblk1)*64, m0 = (blk / nblk1)*64;
    gemm_body<64>(A1, Wt1, b1, C1, nullptr, 0, as1, aq1, g1v, be1,
                  s1, q1, N1, K1, n0, m0, lds, bnS, bnB);
  } else {
    int q = blk - nb1;
    int n0 = (q % nblk2)*64, m0 = (q / nblk2)*64;
    gemm_body<64>(A2, Wt2, b2, C2, nullptr, 0, as2, aq2, g2v, be2,
                  s2, q2, N2, K2, n0, m0, lds, bnS, bnB);
  }
}

// ---------------- adapter core: 16 rows/block, 512 threads, slim LDS (3 blocks/CU) -------
// Phase order: tables+stage aS -> activate aS -> P (aS + u0t from L2) -> stage Hs
// (OVERWRITES aS region) -> q -> t1 -> s -> z2. PT/QS buffers ping-pong.
#define HSTR 1056
__global__ __launch_bounds__(512) void adapter_core(const u16* __restrict__ H,
                                                    const u16* __restrict__ Mout,
                                                    const u16* __restrict__ u0t,
                                                    const float* __restrict__ v0,
                                                    const float* __restrict__ u1,
                                                    const float* __restrict__ ab0,
                                                    const float* __restrict__ hsums,
                                                    const float* __restrict__ hsumsq,
                                                    const float* __restrict__ hg,
                                                    const float* __restrict__ hbe,
                                                    const float* __restrict__ msums,
                                                    const float* __restrict__ msumsq,
                                                    const float* __restrict__ mg,
                                                    const float* __restrict__ mbe,
                                                    u16* __restrict__ Z2){
  __shared__ __align__(16) u16 Hs[16*HSTR];      // 33 KB; first 4096 u16 alias aS
  __shared__ float bnS[1024], bnB[1024];         // 8 KB
  __shared__ __align__(8) u16 v0s[1024], u1s[1024];  // 4 KB
  __shared__ float mS[256], mB[256];             // 2 KB
  __shared__ float PT[512], QS[512];             // 4 KB (Ps->t1s, qs->ss)
  __shared__ float ab0s[32];
  int tid = threadIdx.x;
  int r = tid >> 5, j = tid & 31;
  size_t row0 = (size_t)blockIdx.x * 16;
  u16* aS = Hs;   // alias: aS dead before Hs staged

  // phase A: tables + stage raw Mout
  for (int k = tid; k < 1024; k += 512){
    float mean = hsums[k] * (1.f/(float)BATCH);
    float var  = hsumsq[k] * (1.f/(float)BATCH) - mean*mean;
    float sc   = hg[k] * rsqrtf(var + 1e-5f);
    bnS[k] = sc; bnB[k] = hbe[k] - mean*sc;
  }
  if (tid < 256){
    float4 a = *(const float4*)(v0 + tid*4);
    ushort4 pa = { f2b(a.x), f2b(a.y), f2b(a.z), f2b(a.w) };
    *(ushort4*)&v0s[tid*4] = pa;
    float4 b4 = *(const float4*)(u1 + tid*4);
    ushort4 pb = { f2b(b4.x), f2b(b4.y), f2b(b4.z), f2b(b4.w) };
    *(ushort4*)&u1s[tid*4] = pb;
  } else {
    int c = tid - 256;
    float mean = msums[c] * (1.f/(float)BATCH);
    float var  = msumsq[c] * (1.f/(float)BATCH) - mean*mean;
    float sc   = mg[c] * rsqrtf(var + 1e-5f);
    mS[c] = sc; mB[c] = mbe[c] - mean*sc;
  }
  {
    int el = tid*8;
    uint4 mv = *(const uint4*)(Mout + row0*256 + el);
    *(uint4*)&aS[el] = mv;
  }
  if (tid < 32) ab0s[tid] = ab0[tid];
  __syncthreads();

  // phase B: activate aS in place
  {
    int el = tid*8, col = el & 255;
    u16 mt[8]; __builtin_memcpy(mt, &aS[el], 16);
#pragma unroll
    for (int q=0;q<8;q++){
      float v = b2f(mt[q]) * mS[col+q] + mB[col+q];
      mt[q] = f2b(v > 0.f ? v : 0.f);
    }
    uint4 so; __builtin_memcpy(&so, mt, 16);
    *(uint4*)&aS[el] = so;
  }
  __syncthreads();

  // phase C: P[r][j] = sum_k aS[r][k] * u0t[j][k]  (u0t from L2)
  {
    float acc = 0.f;
    for (int k8 = 0; k8 < 256; k8 += 8){
      uint4 vu = *(const uint4*)(u0t + j*256 + k8);
      uint4 va; __builtin_memcpy(&va, &aS[r*256 + k8], 16);
      u16 ta[8], tu[8]; __builtin_memcpy(ta, &va, 16); __builtin_memcpy(tu, &vu, 16);
#pragma unroll
      for (int q=0;q<8;q++) acc += b2f(ta[q]) * b2f(tu[q]);
    }
    PT[tid] = acc;
  }
  __syncthreads();                 // P visible; aS dead

  // phase D: Hs = relu(bn(H)) — overwrites aS region
#pragma unroll
  for (int it=0; it<4; it++){
    int el = it*4096 + tid*8;
    int rr = el >> 10, col = el & 1023;
    uint4 hv = *(const uint4*)(H + row0*1024 + el);
    u16 ht[8]; __builtin_memcpy(ht, &hv, 16);
#pragma unroll
    for (int q=0;q<8;q++){
      float v = b2f(ht[q]) * bnS[col+q] + bnB[col+q];
      ht[q] = f2b(v > 0.f ? v : 0.f);
    }
    uint4 so; __builtin_memcpy(&so, ht, 16);
    *(uint4*)&Hs[rr*HSTR + col] = so;
  }
  __syncthreads();

  // q[j] = sum_i P[i] H[i,j]
  float acc = 0.f;
#pragma unroll
  for (int i=0;i<32;i++) acc += PT[r*32+i] * b2f(Hs[r*HSTR + i*32 + j]);
  QS[tid] = acc;
  __syncthreads();
  // t1 = sigmoid(q @ v0 + ab0)   (writes PT)
  acc = ab0s[j];
#pragma unroll
  for (int i=0;i<32;i++) acc += QS[r*32+i] * b2f(v0s[i*32+j]);
  PT[tid] = 1.f / (1.f + __expf(-acc));
  __syncthreads();
  // s = t1 @ u1                  (writes QS)
  acc = 0.f;
#pragma unroll
  for (int i=0;i<32;i++) acc += PT[r*32+i] * b2f(u1s[i*32+j]);
  QS[tid] = acc;
  __syncthreads();
  // z2[j] = sum_i s[i] H[i,j]
  acc = 0.f;
#pragma unroll
  for (int i=0;i<32;i++) acc += QS[r*32+i] * b2f(Hs[r*HSTR + i*32 + j]);
  Z2[(row0 + r)*32 + j] = f2b(acc);
}

// ---------------- final head ----------------
__global__ __launch_bounds__(256) void final_kernel(const u16* __restrict__ e,
                                                    const float* __restrict__ cw,
                                                    const float* __restrict__ cb,
                                                    const u16* __restrict__ t,
                                                    const u16* __restrict__ mo,
                                                    const float* __restrict__ tsums,
                                                    const float* __restrict__ tsumsq,
                                                    const float* __restrict__ tg,
                                                    const float* __restrict__ tbe,
                                                    const float* __restrict__ msums,
                                                    const float* __restrict__ msumsq,
                                                    const float* __restrict__ mg,
                                                    const float* __restrict__ mbe,
                                                    const float* __restrict__ lw,
                                                    const float* __restrict__ lb,
                                                    float* __restrict__ out){
  __shared__ float tS[256], tB[256], mS[256], mB[256];
  int tid = threadIdx.x;
  {
    int c = tid;
    float mean = tsums[c] * (1.f/(float)BATCH);
    float var  = (tsumsq[c] - mean*mean*(float)BATCH) * (1.f/(float)(BATCH-1));
    float sc   = tg[c] * rsqrtf(var + 1e-5f);
    tS[c] = sc; tB[c] = tbe[c] - mean*sc;
    float mmean = msums[c] * (1.f/(float)BATCH);
    float mvar  = msumsq[c] * (1.f/(float)BATCH) - mmean*mmean;
    float msc   = mg[c] * rsqrtf(mvar + 1e-5f);
    mS[c] = msc; mB[c] = mbe[c] - mmean*msc;
  }
  __syncthreads();
  int wave = tid >> 6, lane = tid & 63;
  int b = blockIdx.x*4 + wave;
  int n4 = lane*4;
  ushort4 ev = *(const ushort4*)(e + (size_t)b*256 + n4);
  float ec[4] = { b2f(ev.x), b2f(ev.y), b2f(ev.z), b2f(ev.w) };
  float x[4]  = { ec[0], ec[1], ec[2], ec[3] };
  for (int i=0;i<3;i++){
    float p = 0.f;
#pragma unroll
    for (int q=0;q<4;q++) p += x[q] * cw[i*256 + n4 + q];
#pragma unroll
    for (int o=1;o<64;o<<=1) p += __shfl_xor(p, o, 64);
#pragma unroll
    for (int q=0;q<4;q++) x[q] = ec[q]*p + cb[i*256 + n4 + q] + x[q];
  }
  ushort4 tv = *(const ushort4*)(t  + (size_t)b*256 + n4);
  ushort4 mv = *(const ushort4*)(mo + (size_t)b*256 + n4);
  float ta[4] = { b2f(tv.x), b2f(tv.y), b2f(tv.z), b2f(tv.w) };
  float ma[4] = { b2f(mv.x), b2f(mv.y), b2f(mv.z), b2f(mv.w) };
  float p = 0.f;
#pragma unroll
  for (int q=0;q<4;q++){
    int n = n4 + q;
    p += x[q] * lw[n];
    float mr = ma[q]*mS[n] + mB[n];
    mr = mr > 0.f ? mr : 0.f;
    float mf = tS[n]*ta[q] + tB[n] + mr;
    p += mf * lw[256 + n];
  }
#pragma unroll
  for (int o=32;o>0;o>>=1) p += __shfl_down(p, o, 64);
  if (lane == 0){
    float y = p + lb[0];
    out[b] = 1.f / (1.f + __expf(-y));
  }
}

extern "C" void kernel_launch(void* const* d_in, const int* in_sizes, int n_in,
                              void* d_out, int out_size, void* d_ws, size_t ws_size,
                              hipStream_t stream) {
  const int B = BATCH;
  const int*   feat = (const int*)d_in[0];
  const float* emb  = (const float*)d_in[2];
  const float* hW0 = (const float*)d_in[3],  *hb0 = (const float*)d_in[4],  *hg0 = (const float*)d_in[5],  *hbe0 = (const float*)d_in[6];
  const float* hW1 = (const float*)d_in[7],  *hb1 = (const float*)d_in[8],  *hg1 = (const float*)d_in[9],  *hbe1 = (const float*)d_in[10];
  const float* hW2 = (const float*)d_in[11], *hb2 = (const float*)d_in[12], *hg2 = (const float*)d_in[13], *hbe2 = (const float*)d_in[14];
  const float* cw  = (const float*)d_in[15], *cb  = (const float*)d_in[16];
  const float* mW0 = (const float*)d_in[17], *mb0 = (const float*)d_in[18], *mg0 = (const float*)d_in[19], *mbe0 = (const float*)d_in[20];
  const float* mW1 = (const float*)d_in[21], *mb1 = (const float*)d_in[22], *mg1 = (const float*)d_in[23], *mbe1 = (const float*)d_in[24];
  const float* u0  = (const float*)d_in[25], *u1  = (const float*)d_in[26];
  const float* v0  = (const float*)d_in[27], *v1  = (const float*)d_in[28];
  const float* ab0 = (const float*)d_in[29], *ab1 = (const float*)d_in[30];
  const float* gamma1 = (const float*)d_in[31], *bias1 = (const float*)d_in[32];
  const float* lw  = (const float*)d_in[33], *lb = (const float*)d_in[34];
  float* out = (float*)d_out;

  // ---- disjoint workspace layout (~89 MB) ----
  char* base = (char*)d_ws;
  const size_t MB = 1024*1024;
  u16* H    = (u16*)(base);             // [B,1024]  32 MB
  u16* e    = (u16*)(base + 32*MB);     // [B,256]
  u16* Y0   = (u16*)(base + 40*MB);     // [B,128]
  u16* Y1   = (u16*)(base + 44*MB);     // [B,64]
  u16* M0   = (u16*)(base + 48*MB);     // [B,512]
  u16* Mout = (u16*)(base + 64*MB);     // [B,256]
  u16* T    = (u16*)(base + 72*MB);     // [B,256]
  u16* Z2   = (u16*)(base + 80*MB);     // [B,32]
  u16* catWt= (u16*)(base + 88*MB);     // [640][256]
  u16* hW1t = catWt + 163840;           // [64][128]
  u16* hW2t = hW1t + 8192;              // [1024][64]
  u16* mW1t = hW2t + 65536;             // [256][512]
  u16* u0t  = mW1t + 131072;            // [32][256]
  u16* v1t  = u0t + 8192;               // [256][32]
  float* catb = (float*)(v1t + 8192);   // [640]
  float* S    = catb + 640;             // 4480 floats of stats

  // 1. prep
  prep_kernel<<<2547, 256, 0, stream>>>(S, hb0, mb0, catb,
                                        hW0, hW1, hW2, mW0, mW1, u0, v1,
                                        catWt, hW1t, hW2t, mW1t, u0t, v1t,
                                        feat, emb, e);

  // 2. concatenated first layer: e -> {Y0 (cols<128), M0 (cols>=128)}  [N=640, K=256]
  gemm_mfma<64><<<dim3(10, B/64), 256, 0, stream>>>(e, catWt, catb, Y0, M0, 128,
      nullptr, nullptr, nullptr, nullptr, S+0, S+640, 640, 256);

  // 3. fused dual GEMM: Y1 [N=64,K=128, 256 blocks] + Mout [N=256,K=512, 1024 blocks]
  gemm_dual<<<1280, 256, 0, stream>>>(
      Y0, hW1t, hb1, Y1, S+0, S+640, hg0, hbe0, S+1280, S+1344, 64, 128, 256, 1,
      M0, mW1t, mb1, Mout, S+128, S+768, mg0, mbe0, S+3456, S+3712, 256, 512, 4);

  // 4. H [N=1024, K=64]
  gemm_mfma<64><<<dim3(16, B/64), 256, 0, stream>>>(Y1, hW2t, hb2, H, nullptr, 0,
      S+1280, S+1344, hg1, hbe1, S+1408, S+2432, 1024, 64);

  // 5. adapter -> Z2, then T = Z2 @ v1 + ab1  [N=256, K=32]
  adapter_core<<<B/16, 512, 0, stream>>>(H, Mout, u0t, v0, u1, ab0,
      S+1408, S+2432, hg2, hbe2, S+3456, S+3712, mg1, mbe1, Z2);
  gemm_mfma<32><<<dim3(4, B/64), 256, 0, stream>>>(Z2, v1t, ab1, T, nullptr, 0,
      nullptr, nullptr, nullptr, nullptr, S+3968, S+4224, 256, 32);

  // 6. final head
  final_kernel<<<B/4, 256, 0, stream>>>(e, cw, cb, T, Mout,
      S+3968, S+4224, gamma1, bias1,
      S+3456, S+3712, mg1, mbe1, lw, lb, out);
}